// Round 1
// baseline (135.385 us; speedup 1.0000x reference)
//
#include <hip/hip_runtime.h>

// Kernel A: one block. Computes the tiny MLP -> knots + control points,
// then expands de Boor into per-interval cubic coefficients in s = xp - t[k].
// ws layout (floats): [0..5] interior knots c1..c6 (= ak[4..9]); [8 + 4*kk + i]
// cubic coeffs (a0,a1,a2,a3) for interval kk = k-3, kk in [0,7).
__global__ void build_params_kernel(const float* __restrict__ a,
                                    const float* __restrict__ W1, const float* __restrict__ b1,
                                    const float* __restrict__ W2, const float* __restrict__ b2,
                                    const float* __restrict__ Ww, const float* __restrict__ bw,
                                    const float* __restrict__ Wk, const float* __restrict__ bk,
                                    float* __restrict__ ws) {
    __shared__ float net1[32];
    __shared__ float net2[32];
    __shared__ float w9[9];
    __shared__ float kraw[7];
    const int tid = threadIdx.x;
    const float av = a[0];
    if (tid < 32) net1[tid] = sinf(av * W1[tid] + b1[tid]);
    __syncthreads();
    if (tid < 32) {
        float s = b2[tid];
        for (int j = 0; j < 32; ++j) s += net1[j] * W2[j * 32 + tid];
        net2[tid] = sinf(s);
    }
    __syncthreads();
    if (tid < 9) {
        float s = bw[tid];
        for (int j = 0; j < 32; ++j) s += net2[j] * Ww[j * 9 + tid];
        w9[tid] = s;
    } else if (tid >= 16 && tid < 23) {
        const int i = tid - 16;
        float s = bk[i];
        for (int j = 0; j < 32; ++j) s += net2[j] * Wk[j * 7 + i];
        kraw[i] = s;
    }
    __syncthreads();
    if (tid == 0) {
        // softmax over kraw (max-subtracted, like jax.nn.softmax), then cumsum
        float mx = kraw[0];
        for (int i = 1; i < 7; ++i) mx = fmaxf(mx, kraw[i]);
        float e[7];
        float sum = 0.f;
        for (int i = 0; i < 7; ++i) { e[i] = expf(kraw[i] - mx); sum += e[i]; }
        const float invsum = 1.f / sum;
        float t[14];
        t[0] = t[1] = t[2] = t[3] = 0.f;
        float cs = 0.f;
        for (int i = 0; i < 7; ++i) { cs += e[i] * invsum; t[4 + i] = cs; }
        t[11] = t[12] = t[13] = 1.f;
        float w10[10];
        w10[0] = 0.f;
        for (int i = 0; i < 9; ++i) w10[1 + i] = w9[i];
        // interior knots for the digitize-style search
        for (int i = 0; i < 6; ++i) ws[i] = t[4 + i];
        ws[6] = 0.f; ws[7] = 0.f;
        // Expand de Boor symbolically per interval k = kk+3, in s = xp - t[k].
        // alpha_{r,j}(xp) = (xp - t[j+k-3]) / (t[j+1+k-r] - t[j+k-3])
        //               = inv * s + (t[k] - t0) * inv
        for (int kk = 0; kk < 7; ++kk) {
            const int k = kk + 3;
            float d[4][4];
            for (int j = 0; j < 4; ++j) {
                d[j][0] = w10[k - 3 + j];
                d[j][1] = 0.f; d[j][2] = 0.f; d[j][3] = 0.f;
            }
            for (int r = 1; r <= 3; ++r) {
                for (int j = 3; j >= r; --j) {
                    const float t0 = t[j + k - 3];
                    const float t1 = t[j + 1 + k - r];
                    const float den = t1 - t0;
                    // den==0 only for zero-width (unreachable) intervals; keep NaN out.
                    const float invd = (den != 0.f) ? (1.f / den) : 0.f;
                    const float a1 = invd;
                    const float a0 = (t[k] - t0) * invd;
                    float nd[4];
                    for (int i = 0; i < 4; ++i) {
                        const float diff = d[j][i] - d[j - 1][i];
                        nd[i] = d[j - 1][i] + a0 * diff;
                    }
                    for (int i = 0; i < 3; ++i) {
                        const float diff = d[j][i] - d[j - 1][i];
                        nd[i + 1] += a1 * diff;
                    }
                    for (int i = 0; i < 4; ++i) d[j][i] = nd[i];
                }
            }
            ws[8 + 4 * kk + 0] = d[3][0];
            ws[8 + 4 * kk + 1] = d[3][1];
            ws[8 + 4 * kk + 2] = d[3][2];
            ws[8 + 4 * kk + 3] = d[3][3];
        }
    }
}

__device__ __forceinline__ float eval_one(float xi, const float cs[6], const float4* tbl) {
    float xp = fminf(fmaxf(xi * 0.57735026918962576f, 0.0f), 0.9999f);
    int kk = 0;
    float tk = 0.f;
#pragma unroll
    for (int i = 0; i < 6; ++i) {
        if (xp >= cs[i]) { kk = i + 1; tk = cs[i]; }
    }
    const float s = xp - tk;
    const float4 cf = tbl[kk];
    return fmaf(fmaf(fmaf(cf.w, s, cf.z), s, cf.y), s, cf.x);
}

// Kernel B: streaming elementwise spline evaluation, float4 vectorized.
__global__ __launch_bounds__(256) void spline_eval_kernel(const float4* __restrict__ x,
                                                          const float* __restrict__ ws,
                                                          float4* __restrict__ out,
                                                          int n4) {
    __shared__ float4 tbl[7];
    if (threadIdx.x < 7) {
        const float4* src = (const float4*)(ws + 8);
        tbl[threadIdx.x] = src[threadIdx.x];
    }
    float cs[6];
#pragma unroll
    for (int i = 0; i < 6; ++i) cs[i] = ws[i];
    __syncthreads();
    const int idx = blockIdx.x * 256 + threadIdx.x;
    if (idx >= n4) return;
    const float4 xv = x[idx];
    float4 r;
    r.x = eval_one(xv.x, cs, tbl);
    r.y = eval_one(xv.y, cs, tbl);
    r.z = eval_one(xv.z, cs, tbl);
    r.w = eval_one(xv.w, cs, tbl);
    out[idx] = r;
}

extern "C" void kernel_launch(void* const* d_in, const int* in_sizes, int n_in,
                              void* d_out, int out_size, void* d_ws, size_t ws_size,
                              hipStream_t stream) {
    const float* x  = (const float*)d_in[0];
    const float* a  = (const float*)d_in[1];
    const float* W1 = (const float*)d_in[2];
    const float* b1 = (const float*)d_in[3];
    const float* W2 = (const float*)d_in[4];
    const float* b2 = (const float*)d_in[5];
    const float* Ww = (const float*)d_in[6];
    const float* bw = (const float*)d_in[7];
    const float* Wk = (const float*)d_in[8];
    const float* bk = (const float*)d_in[9];
    float* ws  = (float*)d_ws;
    float* out = (float*)d_out;

    build_params_kernel<<<1, 64, 0, stream>>>(a, W1, b1, W2, b2, Ww, bw, Wk, bk, ws);

    const int n4 = out_size / 4;  // out_size = 256^3, divisible by 4
    const int blocks = (n4 + 255) / 256;
    spline_eval_kernel<<<blocks, 256, 0, stream>>>((const float4*)x, ws, (float4*)out, n4);
}

// Round 2
// 131.060 us; speedup vs baseline: 1.0330x; 1.0330x over previous
//
#include <hip/hip_runtime.h>

// Fused kernel: every block redundantly computes the tiny MLP -> knot vector ->
// per-interval cubic coefficients (cheap: ~6.5KB of L2-resident weights, ~0.3us
// of mostly-lane-parallel VALU), then grid-strides over the 256^3 volume doing
// a pure streaming map: clamp -> 6-compare interval search -> ds_read_b128 of
// 4 cubic coeffs -> Horner. Memory-bound: 64MB read + 64MB write.
__global__ __launch_bounds__(256) void nsff_fused_kernel(
    const float4* __restrict__ x, float4* __restrict__ out, int n4,
    const float* __restrict__ a,
    const float* __restrict__ W1, const float* __restrict__ b1,
    const float* __restrict__ W2, const float* __restrict__ b2,
    const float* __restrict__ Ww, const float* __restrict__ bw,
    const float* __restrict__ Wk, const float* __restrict__ bk) {
    __shared__ float net1[32];
    __shared__ float net2[32];
    __shared__ float w9s[9];
    __shared__ float kraws[7];
    __shared__ float tsh[14];
    __shared__ float w10s[10];
    __shared__ float4 tbl[7];
    __shared__ float csh[6];

    const int tid = threadIdx.x;

    // ---- Phase 1: parameters (identical in every block) ----
    if (tid < 32) net1[tid] = sinf(a[0] * W1[tid] + b1[tid]);
    __syncthreads();
    if (tid < 32) {
        float s = b2[tid];
#pragma unroll
        for (int j = 0; j < 32; ++j) s += net1[j] * W2[j * 32 + tid];
        net2[tid] = sinf(s);
    }
    __syncthreads();
    if (tid < 9) {
        float s = bw[tid];
#pragma unroll
        for (int j = 0; j < 32; ++j) s += net2[j] * Ww[j * 9 + tid];
        w9s[tid] = s;
    } else if (tid >= 16 && tid < 23) {
        const int i = tid - 16;
        float s = bk[i];
#pragma unroll
        for (int j = 0; j < 32; ++j) s += net2[j] * Wk[j * 7 + i];
        kraws[i] = s;
    }
    __syncthreads();
    if (tid == 0) {
        // softmax (max-subtracted) -> cumsum -> knot vector
        float mx = kraws[0];
        for (int i = 1; i < 7; ++i) mx = fmaxf(mx, kraws[i]);
        float e[7], sum = 0.f;
        for (int i = 0; i < 7; ++i) { e[i] = expf(kraws[i] - mx); sum += e[i]; }
        const float invsum = 1.f / sum;
        tsh[0] = tsh[1] = tsh[2] = tsh[3] = 0.f;
        float cs = 0.f;
        for (int i = 0; i < 7; ++i) { cs += e[i] * invsum; tsh[4 + i] = cs; }
        tsh[11] = tsh[12] = tsh[13] = 1.f;
        w10s[0] = 0.f;
        for (int i = 0; i < 9; ++i) w10s[1 + i] = w9s[i];
        for (int i = 0; i < 6; ++i) csh[i] = tsh[4 + i];
    }
    __syncthreads();
    if (tid < 7) {
        // Symbolic de Boor expansion for interval k = tid+3 in s = xp - t[k].
        const int k = tid + 3;
        float d[4][4];
        for (int j = 0; j < 4; ++j) {
            d[j][0] = w10s[k - 3 + j];
            d[j][1] = 0.f; d[j][2] = 0.f; d[j][3] = 0.f;
        }
        for (int r = 1; r <= 3; ++r) {
            for (int j = 3; j >= r; --j) {
                const float t0 = tsh[j + k - 3];
                const float t1 = tsh[j + 1 + k - r];
                const float den = t1 - t0;
                const float invd = (den != 0.f) ? (1.f / den) : 0.f;  // no NaN from degenerate intervals
                const float a0 = (tsh[k] - t0) * invd;
                float nd[4];
                for (int i = 0; i < 4; ++i) nd[i] = d[j - 1][i] + a0 * (d[j][i] - d[j - 1][i]);
                for (int i = 0; i < 3; ++i) nd[i + 1] += invd * (d[j][i] - d[j - 1][i]);
                for (int i = 0; i < 4; ++i) d[j][i] = nd[i];
            }
        }
        tbl[tid] = make_float4(d[3][0], d[3][1], d[3][2], d[3][3]);
    }
    __syncthreads();

    // ---- Phase 2: streaming eval ----
    float cs[6];
#pragma unroll
    for (int i = 0; i < 6; ++i) cs[i] = csh[i];

    const int stride = gridDim.x * 256;
#pragma unroll 2
    for (int idx = blockIdx.x * 256 + tid; idx < n4; idx += stride) {
        const float4 xv = x[idx];
        float4 r;
#pragma unroll
        for (int c = 0; c < 4; ++c) {
            const float xi = (&xv.x)[c];
            float xp = fminf(fmaxf(xi * 0.57735026918962576f, 0.0f), 0.9999f);
            int kk = 0;
            float tk = 0.f;
#pragma unroll
            for (int i = 0; i < 6; ++i) {
                if (xp >= cs[i]) { kk = i + 1; tk = cs[i]; }
            }
            const float s = xp - tk;
            const float4 cf = tbl[kk];  // 7 entries x 16B -> 28 distinct banks, conflict-free
            (&r.x)[c] = fmaf(fmaf(fmaf(cf.w, s, cf.z), s, cf.y), s, cf.x);
        }
        out[idx] = r;
    }
}

extern "C" void kernel_launch(void* const* d_in, const int* in_sizes, int n_in,
                              void* d_out, int out_size, void* d_ws, size_t ws_size,
                              hipStream_t stream) {
    const float* x  = (const float*)d_in[0];
    const float* a  = (const float*)d_in[1];
    const float* W1 = (const float*)d_in[2];
    const float* b1 = (const float*)d_in[3];
    const float* W2 = (const float*)d_in[4];
    const float* b2 = (const float*)d_in[5];
    const float* Ww = (const float*)d_in[6];
    const float* bw = (const float*)d_in[7];
    const float* Wk = (const float*)d_in[8];
    const float* bk = (const float*)d_in[9];
    float* out = (float*)d_out;

    const int n4 = out_size / 4;  // 256^3 / 4
    const int blocks = 2048;      // 8 blocks/CU, 8 float4 per thread grid-stride
    nsff_fused_kernel<<<blocks, 256, 0, stream>>>((const float4*)x, (float4*)out, n4,
                                                  a, W1, b1, W2, b2, Ww, bw, Wk, bk);
}